// Round 9
// baseline (79.896 us; speedup 1.0000x reference)
//
#include <hip/hip_runtime.h>

typedef float f32x4 __attribute__((ext_vector_type(4)));

// Quad-permute via DPP (VALU-rate cross-lane within each group of 4 lanes).
template<int CTRL>
__device__ __forceinline__ float qperm(float v) {
    int i = __builtin_bit_cast(int, v);
    i = __builtin_amdgcn_update_dpp(0, i, CTRL, 0xF, 0xF, true);
    return __builtin_bit_cast(float, i);
}

template<int CTRL>
__device__ __forceinline__ f32x4 qperm4(f32x4 v) {
    f32x4 r;
    r.x = qperm<CTRL>(v.x);
    r.y = qperm<CTRL>(v.y);
    r.z = qperm<CTRL>(v.z);
    r.w = qperm<CTRL>(v.w);
    return r;
}

// Compute output row r of  [R|T;0001] @ E  given gathered se3 row (q0,q1,sh)
// and this lane's ext row E (other quad rows fetched via DPP).
__device__ __forceinline__ f32x4 row_apply(int r, f32x4 E, f32x4 q0, f32x4 q1, bool sh) {
    float tx = sh ? q0.z : q0.x;
    float ty = sh ? q0.w : q0.y;
    float tz = sh ? q1.x : q0.z;
    float x  = sh ? q1.y : q0.w;
    float y  = sh ? q1.z : q1.x;
    float z  = sh ? q1.w : q1.y;

    float dot   = x*x + y*y + z*z;
    float t2    = fmaxf(dot, 1e-4f);
    float inv   = rsqrtf(t2);
    float theta = t2 * inv;          // sqrt(t2)
    float s = __sinf(theta);
    float c = __cosf(theta);
    float A  = s * inv;
    float Bc = (1.0f - c) * inv * inv;
    float Cc = (theta - s) * inv * inv * inv;

    float xx = x*x, yy = y*y, zz = z*z;
    float xy = x*y, xz = x*z, yz = y*z;

    bool r0 = (r == 0), r1 = (r == 1), r2 = (r == 2), r3 = (r == 3);
    float kr0 = r1 ?  z : r2 ? -y : 0.0f;
    float kr1 = r0 ? -z : r2 ?  x : 0.0f;
    float kr2 = r0 ?  y : r1 ? -x : 0.0f;
    float k20 = r0 ? -(yy + zz) : r1 ? xy : r2 ? xz : 0.0f;
    float k21 = r0 ? xy : r1 ? -(xx + zz) : r2 ? yz : 0.0f;
    float k22 = r0 ? xz : r1 ? yz : r2 ? -(xx + yy) : 0.0f;
    float d0 = r0 ? 1.0f : 0.0f;
    float d1 = r1 ? 1.0f : 0.0f;
    float d2 = r2 ? 1.0f : 0.0f;

    float R0 = d0 + A*kr0 + Bc*k20;
    float R1 = d1 + A*kr1 + Bc*k21;
    float R2 = d2 + A*kr2 + Bc*k22;
    float V0 = d0 + Bc*kr0 + Cc*k20;
    float V1 = d1 + Bc*kr1 + Cc*k21;
    float V2 = d2 + Bc*kr2 + Cc*k22;
    float T  = V0*tx + V1*ty + V2*tz;

    float m0 = R0, m1 = R1, m2 = R2;
    float m3 = r3 ? 1.0f : T;

    // coefficients in quad-rotation order: ck = M[r][(r+k)&3]
    float c0 = r0 ? m0 : r1 ? m1 : r2 ? m2 : m3;
    float c1 = r0 ? m1 : r1 ? m2 : r2 ? m3 : m0;
    float c2 = r0 ? m2 : r1 ? m3 : r2 ? m0 : m1;
    float c3 = r0 ? m3 : r1 ? m0 : r2 ? m1 : m2;

    f32x4 E1 = qperm4<0x39>(E);   // lane r gets E row (r+1)&3
    f32x4 E2 = qperm4<0x4E>(E);   // (r+2)&3
    f32x4 E3 = qperm4<0x93>(E);   // (r+3)&3

    return c0*E + c1*E1 + c2*E2 + c3*E3;
}

__global__ __launch_bounds__(256) void se3_apply_quad2(
    const float* __restrict__ ext,   // [B,4,4]
    const float* __restrict__ se3,   // [N,6]
    const int*   __restrict__ idx,   // [B]
    float*       __restrict__ out,   // [B,4,4]
    int B, int N)
{
    const int t = threadIdx.x;
    const long rows  = (long)B * 4;
    const long base  = (long)blockIdx.x * 512;
    const long row0  = base + t;          // lane-contiguous
    const long row1  = base + t + 256;    // lane-contiguous
    const int  r     = t & 3;             // quad row (same for both halves)
    const long cr0   = row0 < rows ? row0 : 0;
    const long cr1   = row1 < rows ? row1 : 0;

    // ---- issue BOTH idx loads (independent chains) ----
    int j0 = idx[cr0 >> 2];
    int j1 = idx[cr1 >> 2];

    // ---- issue BOTH ext row loads ----
    const f32x4* extv = reinterpret_cast<const f32x4*>(ext);
    f32x4 E0 = __builtin_nontemporal_load(&extv[cr0]);
    f32x4 E1 = __builtin_nontemporal_load(&extv[cr1]);

    // ---- issue BOTH se3 gathers (two aligned 16B loads each) ----
    const char* se3c = reinterpret_cast<const char*>(se3);
    size_t total = (size_t)N * 24;

    size_t byte0 = (size_t)j0 * 24;
    size_t base0 = byte0 & ~(size_t)15;
    if (base0 + 32 > total) base0 = total - 32;
    f32x4 a0 = *reinterpret_cast<const f32x4*>(se3c + base0);
    f32x4 a1 = *reinterpret_cast<const f32x4*>(se3c + base0 + 16);
    bool sh0 = (byte0 != base0);

    size_t byte1 = (size_t)j1 * 24;
    size_t base1 = byte1 & ~(size_t)15;
    if (base1 + 32 > total) base1 = total - 32;
    f32x4 b0 = *reinterpret_cast<const f32x4*>(se3c + base1);
    f32x4 b1 = *reinterpret_cast<const f32x4*>(se3c + base1 + 16);
    bool sh1 = (byte1 != base1);

    // ---- compute both rows ----
    f32x4 o0 = row_apply(r, E0, a0, a1, sh0);
    f32x4 o1 = row_apply(r, E1, b0, b1, sh1);

    f32x4* outv = reinterpret_cast<f32x4*>(out);
    if (row0 < rows) __builtin_nontemporal_store(o0, &outv[row0]);
    if (row1 < rows) __builtin_nontemporal_store(o1, &outv[row1]);
}

extern "C" void kernel_launch(void* const* d_in, const int* in_sizes, int n_in,
                              void* d_out, int out_size, void* d_ws, size_t ws_size,
                              hipStream_t stream) {
    const float* ext = (const float*)d_in[0];   // [B,4,4]
    const float* se3 = (const float*)d_in[1];   // [N,6]
    const int*   idx = (const int*)d_in[2];     // [B]
    float* out = (float*)d_out;

    int B = in_sizes[2];
    int N = in_sizes[1] / 6;
    long rows = (long)B * 4;                    // one float4-row per work item
    int grid = (int)((rows + 511) / 512);       // 512 rows per 256-thread block
    se3_apply_quad2<<<grid, 256, 0, stream>>>(ext, se3, idx, out, B, N);
}

// Round 10
// 79.267 us; speedup vs baseline: 1.0079x; 1.0079x over previous
//
#include <hip/hip_runtime.h>

typedef float f32x4 __attribute__((ext_vector_type(4)));
typedef int   i32x4 __attribute__((ext_vector_type(4)));

// gfx940+/gfx950 cache-policy bits (LLVM CPol): SC0=1, NT=2, SC1=16.
// NT|SC1 = stream / no-allocate hint for both L2 and LLC paths.
#define CPOL_STREAM 18

#if __has_builtin(__builtin_amdgcn_make_buffer_rsrc) && \
    __has_builtin(__builtin_amdgcn_raw_ptr_buffer_load_b128) && \
    __has_builtin(__builtin_amdgcn_raw_ptr_buffer_store_b128)
#define HAVE_BUFFER 1
#else
#define HAVE_BUFFER 0
#endif

// Quad-permute via DPP (VALU-rate cross-lane within each group of 4 lanes).
template<int CTRL>
__device__ __forceinline__ float qperm(float v) {
    int i = __builtin_bit_cast(int, v);
    i = __builtin_amdgcn_update_dpp(0, i, CTRL, 0xF, 0xF, true);
    return __builtin_bit_cast(float, i);
}

template<int CTRL>
__device__ __forceinline__ f32x4 qperm4(f32x4 v) {
    f32x4 r;
    r.x = qperm<CTRL>(v.x);
    r.y = qperm<CTRL>(v.y);
    r.z = qperm<CTRL>(v.z);
    r.w = qperm<CTRL>(v.w);
    return r;
}

__global__ __launch_bounds__(256) void se3_apply_quad_np(
    const float* __restrict__ ext,   // [B,4,4]
    const float* __restrict__ se3,   // [N,6]
    const int*   __restrict__ idx,   // [B]
    float*       __restrict__ out,   // [B,4,4]
    int B, int N)
{
    const long tid = (long)blockIdx.x * 256 + threadIdx.x;  // global float4-row id
    const long m   = tid >> 2;        // matrix index
    const int  r   = (int)(tid & 3);  // row within matrix
    if (m >= B) return;

    // idx + se3 gather use DEFAULT cache policy -> table allocates in L2/L3
    // and stays resident while the streams bypass.
    int j = idx[m];

    // ---- ext row r: streaming load, no-allocate policy ----
    f32x4 E;
#if HAVE_BUFFER
    __amdgpu_buffer_rsrc_t rext = __builtin_amdgcn_make_buffer_rsrc(
        const_cast<float*>(ext), (short)0, (int)((long)B * 64), 0x00020000);
    {
        i32x4 Ei = __builtin_amdgcn_raw_ptr_buffer_load_b128(
            rext, (int)(tid * 16), 0, CPOL_STREAM);
        E = __builtin_bit_cast(f32x4, Ei);
    }
#else
    {
        const f32x4* extv = reinterpret_cast<const f32x4*>(ext);
        E = __builtin_nontemporal_load(&extv[tid]);
    }
#endif

    // ---- gather se3 row as two aligned 16B loads (default policy) ----
    size_t byte  = (size_t)j * 24;
    size_t base  = byte & ~(size_t)15;
    size_t total = (size_t)N * 24;
    if (base + 32 > total) base = total - 32;   // clamp keeps phase in {0,8}
    const char* se3c = reinterpret_cast<const char*>(se3);
    f32x4 q0 = *reinterpret_cast<const f32x4*>(se3c + base);
    f32x4 q1 = *reinterpret_cast<const f32x4*>(se3c + base + 16);
    bool sh = (byte != base);

    float tx = sh ? q0.z : q0.x;
    float ty = sh ? q0.w : q0.y;
    float tz = sh ? q1.x : q0.z;
    float x  = sh ? q1.y : q0.w;
    float y  = sh ? q1.z : q1.x;
    float z  = sh ? q1.w : q1.y;

    // ---- se3 exp map coefficients (reference semantics: clip(dot, EPS)) ----
    float dot   = x*x + y*y + z*z;
    float t2    = fmaxf(dot, 1e-4f);
    float inv   = rsqrtf(t2);
    float theta = t2 * inv;          // sqrt(t2)
    float s = __sinf(theta);
    float c = __cosf(theta);
    float A  = s * inv;
    float Bc = (1.0f - c) * inv * inv;
    float Cc = (theta - s) * inv * inv * inv;

    float xx = x*x, yy = y*y, zz = z*z;
    float xy = x*y, xz = x*z, yz = y*z;

    // This lane only needs ROW r of K and K^2.
    bool r0 = (r == 0), r1 = (r == 1), r2 = (r == 2), r3 = (r == 3);
    float kr0 = r1 ?  z : r2 ? -y : 0.0f;
    float kr1 = r0 ? -z : r2 ?  x : 0.0f;
    float kr2 = r0 ?  y : r1 ? -x : 0.0f;
    float k20 = r0 ? -(yy + zz) : r1 ? xy : r2 ? xz : 0.0f;
    float k21 = r0 ? xy : r1 ? -(xx + zz) : r2 ? yz : 0.0f;
    float k22 = r0 ? xz : r1 ? yz : r2 ? -(xx + yy) : 0.0f;
    float d0 = r0 ? 1.0f : 0.0f;
    float d1 = r1 ? 1.0f : 0.0f;
    float d2 = r2 ? 1.0f : 0.0f;

    // Row r of R = I + A*K + Bc*K^2  (all-zero for r==3)
    float R0 = d0 + A*kr0 + Bc*k20;
    float R1 = d1 + A*kr1 + Bc*k21;
    float R2 = d2 + A*kr2 + Bc*k22;
    // Row r of V = I + Bc*K + Cc*K^2, then T_r = V_r . t
    float V0 = d0 + Bc*kr0 + Cc*k20;
    float V1 = d1 + Bc*kr1 + Cc*k21;
    float V2 = d2 + Bc*kr2 + Cc*k22;
    float T  = V0*tx + V1*ty + V2*tz;

    float m0 = R0, m1 = R1, m2 = R2;
    float m3 = r3 ? 1.0f : T;

    // coefficients in quad-rotation order: ck = M[r][(r+k)&3]
    float c0 = r0 ? m0 : r1 ? m1 : r2 ? m2 : m3;
    float c1 = r0 ? m1 : r1 ? m2 : r2 ? m3 : m0;
    float c2 = r0 ? m2 : r1 ? m3 : r2 ? m0 : m1;
    float c3 = r0 ? m3 : r1 ? m0 : r2 ? m1 : m2;

    // Other quad rows of E via DPP quad_perm rotations.
    f32x4 E1 = qperm4<0x39>(E);   // lane r gets E row (r+1)&3
    f32x4 E2 = qperm4<0x4E>(E);   // (r+2)&3
    f32x4 E3 = qperm4<0x93>(E);   // (r+3)&3

    f32x4 o = c0*E + c1*E1 + c2*E2 + c3*E3;

    // ---- streaming store, no-allocate policy ----
#if HAVE_BUFFER
    __amdgpu_buffer_rsrc_t rout = __builtin_amdgcn_make_buffer_rsrc(
        out, (short)0, (int)((long)B * 64), 0x00020000);
    __builtin_amdgcn_raw_ptr_buffer_store_b128(
        __builtin_bit_cast(i32x4, o), rout, (int)(tid * 16), 0, CPOL_STREAM);
#else
    {
        f32x4* outv = reinterpret_cast<f32x4*>(out);
        __builtin_nontemporal_store(o, &outv[tid]);
    }
#endif
}

extern "C" void kernel_launch(void* const* d_in, const int* in_sizes, int n_in,
                              void* d_out, int out_size, void* d_ws, size_t ws_size,
                              hipStream_t stream) {
    const float* ext = (const float*)d_in[0];   // [B,4,4]
    const float* se3 = (const float*)d_in[1];   // [N,6]
    const int*   idx = (const int*)d_in[2];     // [B]
    float* out = (float*)d_out;

    int B = in_sizes[2];
    int N = in_sizes[1] / 6;
    long rows = (long)B * 4;                    // one float4-row per thread
    int grid = (int)((rows + 255) / 256);
    se3_apply_quad_np<<<grid, 256, 0, stream>>>(ext, se3, idx, out, B, N);
}